// Round 6
// baseline (332.521 us; speedup 1.0000x reference)
//
#include <hip/hip_runtime.h>
#include <hip/hip_fp16.h>

#define HW 4096
#define NC 192
#define NB 8
#define DQK 32   // padded qk depth (24 real + 8 zero)
#define LOG2E 1.4426950408889634f
#define THRL 11.541560327f   // 8 * log2e (defer-max threshold, log2 domain)

typedef _Float16 f16x8 __attribute__((ext_vector_type(8)));
typedef float f32x4 __attribute__((ext_vector_type(4)));
typedef unsigned int u32x4 __attribute__((ext_vector_type(4)));

// raw barrier with compiler memory fences on both sides; does NOT drain vmcnt,
// so prefetched global loads stay in flight across it.
#define BAR() do { asm volatile("s_waitcnt lgkmcnt(0)" ::: "memory"); \
                   __builtin_amdgcn_s_barrier();                      \
                   asm volatile("" ::: "memory"); } while (0)

static __device__ __forceinline__ unsigned int pkrtz(float a, float b) {
  auto h = __builtin_amdgcn_cvt_pkrtz(a, b);
  return __builtin_bit_cast(unsigned int, h);
}
static __device__ __forceinline__ unsigned short f2h_bits(float f) {
  _Float16 h = (_Float16)f;  // RTE
  union { _Float16 h; unsigned short u; } cv; cv.h = h; return cv.u;
}

// ---------------- weight transpose: wt[c][och] (c-major) + bias row (192) + slope row (193)
__global__ void wtrans_kernel(
    const float* __restrict__ w1, const float* __restrict__ b1, const float* __restrict__ a1,
    const float* __restrict__ w2, const float* __restrict__ b2, const float* __restrict__ a2,
    const float* __restrict__ wa, const float* __restrict__ ba, const float* __restrict__ aa,
    float* __restrict__ wt)
{
  const int c = blockIdx.x;     // 0..193
  const int o = threadIdx.x;    // 0..255
  if (o >= 240) return;
  float v;
  if (c < 192) {
    if (o < 24)      v = w1[o * 192 + c];
    else if (o < 48) v = w2[(o - 24) * 192 + c];
    else             v = wa[(o - 48) * 192 + c];
  } else if (c == 192) {
    v = (o < 24) ? b1[o] : (o < 48) ? b2[o - 24] : ba[o - 48];
  } else {
    v = (o < 24) ? a1[0] : (o < 48) ? a2[0] : aa[0];
  }
  wt[c * 240 + o] = v;
}

// ---------------- projection: thread = 2 positions x 16 out-channels, weights via scalar loads
__global__ __launch_bounds__(256) void proj_kernel(
    const float* __restrict__ x, const float* __restrict__ wt,
    unsigned short* __restrict__ Qn, unsigned short* __restrict__ Kn,
    unsigned short* __restrict__ Vt)
{
  const int g   = blockIdx.y;                       // 16-channel group 0..14
  const int tid = threadIdx.x;
  const int bp  = (blockIdx.x * 256 + tid) * 2;     // first of 2 positions
  const int b   = bp >> 12;                         // uniform per block
  const int pos = bp & (HW - 1);

  const float* xb = x + (size_t)b * NC * HW + pos;
  float acc0[16], acc1[16];
  #pragma unroll
  for (int o = 0; o < 16; ++o) { acc0[o] = 0.f; acc1[o] = 0.f; }

  #pragma unroll 4
  for (int c = 0; c < 192; ++c) {
    float2 xv = *reinterpret_cast<const float2*>(xb + (size_t)c * HW);
    const float* wr = wt + c * 240 + g * 16;        // wave-uniform address -> s_load
    #pragma unroll
    for (int o = 0; o < 16; ++o) {
      float w = wr[o];
      acc0[o] = fmaf(w, xv.x, acc0[o]);
      acc1[o] = fmaf(w, xv.y, acc1[o]);
    }
  }

  const float* brow = wt + 192 * 240 + g * 16;
  const float* srow = wt + 193 * 240 + g * 16;
  unsigned short h0[16], h1[16];
  #pragma unroll
  for (int o = 0; o < 16; ++o) {
    float bias = brow[o], sm1 = srow[o] - 1.f;
    float v0 = acc0[o] + bias; v0 += fminf(v0, 0.f) * sm1;
    float v1 = acc1[o] + bias; v1 += fminf(v1, 0.f) * sm1;
    if (g * 16 + o < 24) { v0 *= LOG2E; v1 *= LOG2E; }   // pre-scale Q for log2-domain softmax
    h0[o] = f2h_bits(v0);
    h1[o] = f2h_bits(v1);
  }

  if (g >= 3) {
    const int vch0 = g * 16 - 48;
    unsigned int* vp = reinterpret_cast<unsigned int*>(
        Vt + ((size_t)b * NC + vch0) * HW + pos);
    #pragma unroll
    for (int o = 0; o < 16; ++o)
      vp[o * (HW / 2)] = (unsigned int)h0[o] | ((unsigned int)h1[o] << 16);
  } else {
    u32x4 lo0, hi0, lo1, hi1;
    #pragma unroll
    for (int j = 0; j < 4; ++j) {
      lo0[j] = (unsigned int)h0[2 * j] | ((unsigned int)h0[2 * j + 1] << 16);
      hi0[j] = (unsigned int)h0[8 + 2 * j] | ((unsigned int)h0[9 + 2 * j] << 16);
      lo1[j] = (unsigned int)h1[2 * j] | ((unsigned int)h1[2 * j + 1] << 16);
      hi1[j] = (unsigned int)h1[8 + 2 * j] | ((unsigned int)h1[9 + 2 * j] << 16);
    }
    const size_t bpos = (size_t)b * HW + pos;
    if (g == 0) {
      u32x4* q0 = reinterpret_cast<u32x4*>(Qn + bpos * DQK);
      q0[0] = lo0; q0[1] = hi0;
      u32x4* q1 = reinterpret_cast<u32x4*>(Qn + (bpos + 1) * DQK);
      q1[0] = lo1; q1[1] = hi1;
    } else if (g == 1) {
      *reinterpret_cast<u32x4*>(Qn + bpos * DQK + 16) = lo0;
      *reinterpret_cast<u32x4*>(Kn + bpos * DQK) = hi0;
      *reinterpret_cast<u32x4*>(Qn + (bpos + 1) * DQK + 16) = lo1;
      *reinterpret_cast<u32x4*>(Kn + (bpos + 1) * DQK) = hi1;
    } else {
      u32x4* k0 = reinterpret_cast<u32x4*>(Kn + bpos * DQK + 8);
      k0[0] = lo0; k0[1] = hi0;
      u32x4* k1 = reinterpret_cast<u32x4*>(Kn + (bpos + 1) * DQK + 8);
      k1[0] = lo1; k1[1] = hi1;
    }
  }
}

// ---------------- flash attention: 8 waves = 2 m-halves x 4 groups; pipelined,
// one raw barrier per m-tile, double-buffered P exchange, l via ones-MFMA.
__global__ __launch_bounds__(512, 4) void flash_kernel(
    const unsigned short* __restrict__ Qn, const unsigned short* __restrict__ Kn,
    const unsigned short* __restrict__ Vt, float* __restrict__ out)
{
  const int b    = blockIdx.y;
  const int q0   = blockIdx.x * 64;
  const int tid  = threadIdx.x;
  const int w    = tid >> 6;
  const int half = w >> 2;
  const int wi   = w & 3;
  const int lane = tid & 63;
  const int lq   = lane & 15;
  const int lk   = lane >> 4;

  __shared__ u32x4 Pex[2][2][4][2][64];     // [par][half][wi][kk][lane]  32 KB
  __shared__ float alphaL[2][2][4][16];     // [par][half][wi][row]        1 KB
  __shared__ float mlL[2][2][64];           // [half][{m,l}][row]          1 KB

  const int mbase = half * (HW / 2);
  const int sigb  = 8 * (lq >> 2) + (lq & 3);   // sigma permutation base

  f16x8 qfrag = *reinterpret_cast<const f16x8*>(
      Qn + ((size_t)b * HW + q0 + 16 * wi + lq) * DQK + 8 * lk);

  float m = -1e30f;
  f32x4 O[12], lacc;
  #pragma unroll
  for (int i = 0; i < 12; ++i) O[i] = (f32x4){0.f, 0.f, 0.f, 0.f};
  lacc = (f32x4){0.f, 0.f, 0.f, 0.f};

  const unsigned short* Kb = Kn + (size_t)b * HW * DQK + (size_t)sigb * DQK + 8 * lk;
  const unsigned short* Vw = Vt + (size_t)b * NC * HW + (size_t)(wi * 48 + lq) * HW + 8 * lk;

  f16x8 vones;
  #pragma unroll
  for (int i = 0; i < 8; ++i) vones[i] = (_Float16)1.0f;

  f16x8 Kf[4], Vf[6];

  // QK^T (from preloaded Kf) + softmax; writes Pex[par], alphaL[par]
  auto qk_softmax = [&](int par) {
    f32x4 s[4];
    #pragma unroll
    for (int t = 0; t < 4; ++t)
      s[t] = __builtin_amdgcn_mfma_f32_16x16x32_f16(Kf[t], qfrag,
              (f32x4){0.f, 0.f, 0.f, 0.f}, 0, 0, 0);
    float pmax = s[0][0];
    #pragma unroll
    for (int t = 0; t < 4; ++t)
      #pragma unroll
      for (int r = 0; r < 4; ++r) pmax = fmaxf(pmax, s[t][r]);
    pmax = fmaxf(pmax, __shfl_xor(pmax, 16));
    pmax = fmaxf(pmax, __shfl_xor(pmax, 32));
    float alpha = 1.f;
    if (__any(pmax > m + THRL)) {
      float mn = fmaxf(m, pmax);
      alpha = exp2f(m - mn);
      m = mn;
    }
    float p[4][4];
    #pragma unroll
    for (int t = 0; t < 4; ++t)
      #pragma unroll
      for (int r = 0; r < 4; ++r) p[t][r] = exp2f(s[t][r] - m);
    u32x4 pa0, pa1;
    pa0[0] = pkrtz(p[0][0], p[0][1]); pa0[1] = pkrtz(p[0][2], p[0][3]);
    pa0[2] = pkrtz(p[2][0], p[2][1]); pa0[3] = pkrtz(p[2][2], p[2][3]);
    pa1[0] = pkrtz(p[1][0], p[1][1]); pa1[1] = pkrtz(p[1][2], p[1][3]);
    pa1[2] = pkrtz(p[3][0], p[3][1]); pa1[3] = pkrtz(p[3][2], p[3][3]);
    Pex[par][half][wi][0][lane] = pa0;
    Pex[par][half][wi][1][lane] = pa1;
    if (lane < 16) alphaL[par][half][wi][lane] = alpha;
  };

  // ---- prologue: tile 0
  #pragma unroll
  for (int t = 0; t < 4; ++t)
    Kf[t] = *reinterpret_cast<const f16x8*>(
        Kb + (size_t)(mbase + 32 * (t & 1) + 4 * (t >> 1)) * DQK);
  qk_softmax(0);
  #pragma unroll
  for (int kk = 0; kk < 2; ++kk)
    #pragma unroll
    for (int tc = 0; tc < 3; ++tc)
      Vf[kk * 3 + tc] = *reinterpret_cast<const f16x8*>(
          Vw + (size_t)tc * 16 * HW + mbase + kk * 32);
  BAR();

  const int NIT = HW / 2 / 64;   // 32
  for (int it = 0; it < NIT; ++it) {
    const int p = it & 1;
    const bool notlast = (it + 1 < NIT);
    const int mnext = mbase + (it + 1) * 64;
    // prefetch next K (hidden under PV MFMAs)
    if (notlast) {
      #pragma unroll
      for (int t = 0; t < 4; ++t)
        Kf[t] = *reinterpret_cast<const f16x8*>(
            Kb + (size_t)(mnext + 32 * (t & 1) + 4 * (t >> 1)) * DQK);
    }
    // read this tile's P fragments + alphas
    f16x8 paf[2][4];
    #pragma unroll
    for (int kk = 0; kk < 2; ++kk)
      #pragma unroll
      for (int tr = 0; tr < 4; ++tr)
        paf[kk][tr] = __builtin_bit_cast(f16x8, Pex[p][half][tr][kk][lane]);
    #pragma unroll
    for (int tr = 0; tr < 4; ++tr) {
      f32x4 al = *reinterpret_cast<const f32x4*>(&alphaL[p][half][tr][4 * lk]);
      int diff = (al[0] != 1.f) | (al[1] != 1.f) | (al[2] != 1.f) | (al[3] != 1.f);
      if (__any(diff)) {
        #pragma unroll
        for (int tc = 0; tc < 3; ++tc) {
          O[tr * 3 + tc][0] *= al[0]; O[tr * 3 + tc][1] *= al[1];
          O[tr * 3 + tc][2] *= al[2]; O[tr * 3 + tc][3] *= al[3];
        }
        if (tr == wi) {
          lacc[0] *= al[0]; lacc[1] *= al[1]; lacc[2] *= al[2]; lacc[3] *= al[3];
        }
      }
    }
    // PV + l accumulation (MFMA pipe)
    #pragma unroll
    for (int kk = 0; kk < 2; ++kk) {
      #pragma unroll
      for (int tc = 0; tc < 3; ++tc)
        #pragma unroll
        for (int tr = 0; tr < 4; ++tr)
          O[tr * 3 + tc] = __builtin_amdgcn_mfma_f32_16x16x32_f16(
              paf[kk][tr], Vf[kk * 3 + tc], O[tr * 3 + tc], 0, 0, 0);
      f16x8 pw = __builtin_bit_cast(f16x8, Pex[p][half][wi][kk][lane]);
      lacc = __builtin_amdgcn_mfma_f32_16x16x32_f16(pw, vones, lacc, 0, 0, 0);
    }
    // next tile: V loads, QK^T, softmax, P exchange (other parity)
    if (notlast) {
      #pragma unroll
      for (int kk = 0; kk < 2; ++kk)
        #pragma unroll
        for (int tc = 0; tc < 3; ++tc)
          Vf[kk * 3 + tc] = *reinterpret_cast<const f16x8*>(
              Vw + (size_t)tc * 16 * HW + mnext + kk * 32);
      qk_softmax(p ^ 1);
    }
    BAR();
  }

  // ---- cross-half merge, staged through the Pex area (2 chunks)
  if (lane < 16) mlL[half][0][16 * wi + lane] = m;
  if (lq == 0) {
    #pragma unroll
    for (int r = 0; r < 4; ++r) mlL[half][1][16 * wi + 4 * lk + r] = lacc[r];
  }
  f32x4* Ost = reinterpret_cast<f32x4*>(&Pex[0][0][0][0][0]);
  if (half == 1) {
    #pragma unroll
    for (int i = 0; i < 8; ++i) Ost[(wi * 8 + i) * 64 + lane] = O[i];
  }
  BAR();
  f32x4 f0v[4], f1v[4];
  if (half == 0) {
    #pragma unroll
    for (int tr = 0; tr < 4; ++tr) {
      f32x4 m0v = *reinterpret_cast<const f32x4*>(&mlL[0][0][16 * tr + 4 * lk]);
      f32x4 l0v = *reinterpret_cast<const f32x4*>(&mlL[0][1][16 * tr + 4 * lk]);
      f32x4 m1v = *reinterpret_cast<const f32x4*>(&mlL[1][0][16 * tr + 4 * lk]);
      f32x4 l1v = *reinterpret_cast<const f32x4*>(&mlL[1][1][16 * tr + 4 * lk]);
      #pragma unroll
      for (int r = 0; r < 4; ++r) {
        float M  = fmaxf(m0v[r], m1v[r]);
        float s0 = exp2f(m0v[r] - M), s1 = exp2f(m1v[r] - M);
        float L  = s0 * l0v[r] + s1 * l1v[r];
        f0v[tr][r] = s0 / L; f1v[tr][r] = s1 / L;
      }
    }
    #pragma unroll
    for (int i = 0; i < 8; ++i) {
      const int tr = i / 3, tc = i - tr * 3;
      f32x4 o1 = Ost[(wi * 8 + i) * 64 + lane];
      f32x4 o;
      #pragma unroll
      for (int r = 0; r < 4; ++r) o[r] = O[i][r] * f0v[tr][r] + o1[r] * f1v[tr][r];
      *reinterpret_cast<f32x4*>(
          out + ((size_t)b * NC + wi * 48 + tc * 16 + lq) * HW + q0 + 16 * tr + 4 * lk) = o;
    }
  }
  BAR();
  if (half == 1) {
    #pragma unroll
    for (int i = 0; i < 4; ++i) Ost[(wi * 4 + i) * 64 + lane] = O[8 + i];
  }
  BAR();
  if (half == 0) {
    #pragma unroll
    for (int i = 8; i < 12; ++i) {
      const int tr = i / 3, tc = i - tr * 3;
      f32x4 o1 = Ost[(wi * 4 + (i - 8)) * 64 + lane];
      f32x4 o;
      #pragma unroll
      for (int r = 0; r < 4; ++r) o[r] = O[i][r] * f0v[tr][r] + o1[r] * f1v[tr][r];
      *reinterpret_cast<f32x4*>(
          out + ((size_t)b * NC + wi * 48 + tc * 16 + lq) * HW + q0 + 16 * tr + 4 * lk) = o;
    }
  }
}

extern "C" void kernel_launch(void* const* d_in, const int* in_sizes, int n_in,
                              void* d_out, int out_size, void* d_ws, size_t ws_size,
                              hipStream_t stream) {
  const float* x  = (const float*)d_in[0];
  const float* w1 = (const float*)d_in[1];
  const float* b1 = (const float*)d_in[2];
  const float* a1 = (const float*)d_in[3];
  const float* w2 = (const float*)d_in[4];
  const float* b2 = (const float*)d_in[5];
  const float* a2 = (const float*)d_in[6];
  const float* wa = (const float*)d_in[7];
  const float* ba = (const float*)d_in[8];
  const float* aa = (const float*)d_in[9];
  float* out = (float*)d_out;

  unsigned short* Qn = (unsigned short*)d_ws;                 // 2 MB
  unsigned short* Kn = Qn + (size_t)NB * HW * DQK;            // 2 MB
  unsigned short* Vt = Kn + (size_t)NB * HW * DQK;            // 12 MB
  float* wt = out + (out_size - 49152);                       // 194*240 floats used

  (void)hipMemsetAsync(Qn, 0, (size_t)NB * HW * DQK * 2 * sizeof(unsigned short), stream);

  wtrans_kernel<<<dim3(194), 256, 0, stream>>>(w1, b1, a1, w2, b2, a2, wa, ba, aa, wt);

  dim3 pgrid(HW * NB / 512, 15);
  proj_kernel<<<pgrid, 256, 0, stream>>>(x, wt, Qn, Kn, Vt);

  dim3 fgrid(HW / 64, NB);
  flash_kernel<<<fgrid, 512, 0, stream>>>(Qn, Kn, Vt, out);
}

// Round 7
// 183.951 us; speedup vs baseline: 1.8077x; 1.8077x over previous
//
#include <hip/hip_runtime.h>
#include <hip/hip_fp16.h>

#define HW 4096
#define NC 192
#define NB 8
#define DQK 32   // padded qk depth (24 real + 8 zero)
#define LOG2E 1.4426950408889634f
#define THRL 11.541560327f   // 8 * log2e (defer-max threshold, log2 domain)

typedef _Float16 f16x8 __attribute__((ext_vector_type(8)));
typedef float f32x4 __attribute__((ext_vector_type(4)));
typedef unsigned int u32x4 __attribute__((ext_vector_type(4)));

// raw barrier: drains LDS ops only; prefetched global loads stay in flight.
#define BAR() do { asm volatile("s_waitcnt lgkmcnt(0)" ::: "memory"); \
                   __builtin_amdgcn_s_barrier();                      \
                   asm volatile("" ::: "memory"); } while (0)

static __device__ __forceinline__ unsigned int pkrtz(float a, float b) {
  auto h = __builtin_amdgcn_cvt_pkrtz(a, b);
  return __builtin_bit_cast(unsigned int, h);
}
static __device__ __forceinline__ unsigned short f2h_bits(float f) {
  _Float16 h = (_Float16)f;  // RTE
  union { _Float16 h; unsigned short u; } cv; cv.h = h; return cv.u;
}

// ---------------- weight transpose: wt[c][och] (c-major) + bias row (192) + slope row (193)
__global__ void wtrans_kernel(
    const float* __restrict__ w1, const float* __restrict__ b1, const float* __restrict__ a1,
    const float* __restrict__ w2, const float* __restrict__ b2, const float* __restrict__ a2,
    const float* __restrict__ wa, const float* __restrict__ ba, const float* __restrict__ aa,
    float* __restrict__ wt)
{
  const int c = blockIdx.x;     // 0..193
  const int o = threadIdx.x;    // 0..255
  if (o >= 240) return;
  float v;
  if (c < 192) {
    if (o < 24)      v = w1[o * 192 + c];
    else if (o < 48) v = w2[(o - 24) * 192 + c];
    else             v = wa[(o - 48) * 192 + c];
  } else if (c == 192) {
    v = (o < 24) ? b1[o] : (o < 48) ? b2[o - 24] : ba[o - 48];
  } else {
    v = (o < 24) ? a1[0] : (o < 48) ? a2[0] : aa[0];
  }
  wt[c * 240 + o] = v;
}

// ---------------- projection: thread = 2 positions x 16 out-channels, weights via scalar loads
__global__ __launch_bounds__(256) void proj_kernel(
    const float* __restrict__ x, const float* __restrict__ wt,
    unsigned short* __restrict__ Qn, unsigned short* __restrict__ Kn,
    unsigned short* __restrict__ Vt)
{
  const int g   = blockIdx.y;                       // 16-channel group 0..14
  const int tid = threadIdx.x;
  const int bp  = (blockIdx.x * 256 + tid) * 2;     // first of 2 positions
  const int b   = bp >> 12;                         // uniform per block
  const int pos = bp & (HW - 1);

  const float* xb = x + (size_t)b * NC * HW + pos;
  float acc0[16], acc1[16];
  #pragma unroll
  for (int o = 0; o < 16; ++o) { acc0[o] = 0.f; acc1[o] = 0.f; }

  #pragma unroll 4
  for (int c = 0; c < 192; ++c) {
    float2 xv = *reinterpret_cast<const float2*>(xb + (size_t)c * HW);
    const float* wr = wt + c * 240 + g * 16;        // wave-uniform address -> s_load
    #pragma unroll
    for (int o = 0; o < 16; ++o) {
      float w = wr[o];
      acc0[o] = fmaf(w, xv.x, acc0[o]);
      acc1[o] = fmaf(w, xv.y, acc1[o]);
    }
  }

  const float* brow = wt + 192 * 240 + g * 16;
  const float* srow = wt + 193 * 240 + g * 16;
  unsigned short h0[16], h1[16];
  #pragma unroll
  for (int o = 0; o < 16; ++o) {
    float bias = brow[o], sm1 = srow[o] - 1.f;
    float v0 = acc0[o] + bias; v0 += fminf(v0, 0.f) * sm1;
    float v1 = acc1[o] + bias; v1 += fminf(v1, 0.f) * sm1;
    if (g * 16 + o < 24) { v0 *= LOG2E; v1 *= LOG2E; }   // Q pre-scale: log2-domain softmax
    h0[o] = f2h_bits(v0);
    h1[o] = f2h_bits(v1);
  }

  if (g >= 3) {
    const int vch0 = g * 16 - 48;
    unsigned int* vp = reinterpret_cast<unsigned int*>(
        Vt + ((size_t)b * NC + vch0) * HW + pos);
    #pragma unroll
    for (int o = 0; o < 16; ++o)
      vp[o * (HW / 2)] = (unsigned int)h0[o] | ((unsigned int)h1[o] << 16);
  } else {
    u32x4 lo0, hi0, lo1, hi1;
    #pragma unroll
    for (int j = 0; j < 4; ++j) {
      lo0[j] = (unsigned int)h0[2 * j] | ((unsigned int)h0[2 * j + 1] << 16);
      hi0[j] = (unsigned int)h0[8 + 2 * j] | ((unsigned int)h0[9 + 2 * j] << 16);
      lo1[j] = (unsigned int)h1[2 * j] | ((unsigned int)h1[2 * j + 1] << 16);
      hi1[j] = (unsigned int)h1[8 + 2 * j] | ((unsigned int)h1[9 + 2 * j] << 16);
    }
    const size_t bpos = (size_t)b * HW + pos;
    if (g == 0) {
      u32x4* q0 = reinterpret_cast<u32x4*>(Qn + bpos * DQK);
      q0[0] = lo0; q0[1] = hi0;
      u32x4* q1 = reinterpret_cast<u32x4*>(Qn + (bpos + 1) * DQK);
      q1[0] = lo1; q1[1] = hi1;
    } else if (g == 1) {
      *reinterpret_cast<u32x4*>(Qn + bpos * DQK + 16) = lo0;
      *reinterpret_cast<u32x4*>(Kn + bpos * DQK) = hi0;
      *reinterpret_cast<u32x4*>(Qn + (bpos + 1) * DQK + 16) = lo1;
      *reinterpret_cast<u32x4*>(Kn + (bpos + 1) * DQK) = hi1;
    } else {
      u32x4* k0 = reinterpret_cast<u32x4*>(Kn + bpos * DQK + 8);
      k0[0] = lo0; k0[1] = hi0;
      u32x4* k1 = reinterpret_cast<u32x4*>(Kn + (bpos + 1) * DQK + 8);
      k1[0] = lo1; k1[1] = hi1;
    }
  }
}

// ---------------- flash attention: 8 waves = 2 m-halves x 4 groups; pipelined,
// one raw barrier per m-tile, parity-buffered P exchange, l via ones-MFMA.
__global__ __launch_bounds__(512, 4) void flash_kernel(
    const unsigned short* __restrict__ Qn, const unsigned short* __restrict__ Kn,
    const unsigned short* __restrict__ Vt, float* __restrict__ out)
{
  const int b    = blockIdx.y;
  const int q0   = blockIdx.x * 64;
  const int tid  = threadIdx.x;
  const int w    = tid >> 6;
  const int half = w >> 2;
  const int wi   = w & 3;
  const int lane = tid & 63;
  const int lq   = lane & 15;
  const int lk   = lane >> 4;

  __shared__ u32x4 Pex[2][2][4][2][64];     // [par][half][wi][kk][lane]  32 KB
  __shared__ float alphaL[2][2][4][16];     // [par][half][wi][row]        1 KB
  __shared__ float mlL[2][2][64];           // [half][{m,l}][row]          1 KB

  const int mbase = half * (HW / 2);
  const int sigb  = 8 * (lq >> 2) + (lq & 3);   // sigma permutation base

  f16x8 qfrag = *reinterpret_cast<const f16x8*>(
      Qn + ((size_t)b * HW + q0 + 16 * wi + lq) * DQK + 8 * lk);

  float m = -1e30f;
  f32x4 O[12], lacc;
  #pragma unroll
  for (int i = 0; i < 12; ++i) O[i] = (f32x4){0.f, 0.f, 0.f, 0.f};
  lacc = (f32x4){0.f, 0.f, 0.f, 0.f};

  const unsigned short* Kb = Kn + (size_t)b * HW * DQK + (size_t)sigb * DQK + 8 * lk;
  const unsigned short* Vw = Vt + (size_t)b * NC * HW + (size_t)(wi * 48 + lq) * HW + 8 * lk;

  f16x8 vones;
  #pragma unroll
  for (int i = 0; i < 8; ++i) vones[i] = (_Float16)1.0f;

  f16x8 Kf[4];

  // QK^T (from preloaded Kf) + softmax; writes Pex[par], alphaL[par]
  auto qk_softmax = [&](int par) {
    f32x4 s[4];
    #pragma unroll
    for (int t = 0; t < 4; ++t)
      s[t] = __builtin_amdgcn_mfma_f32_16x16x32_f16(Kf[t], qfrag,
              (f32x4){0.f, 0.f, 0.f, 0.f}, 0, 0, 0);
    // local (16-value) max is sufficient for the trigger decision
    float pmax = s[0][0];
    #pragma unroll
    for (int t = 0; t < 4; ++t)
      #pragma unroll
      for (int r = 0; r < 4; ++r) pmax = fmaxf(pmax, s[t][r]);
    float alpha = 1.f;
    if (__any(pmax > m + THRL)) {
      pmax = fmaxf(pmax, __shfl_xor(pmax, 16));   // rare path: row max
      pmax = fmaxf(pmax, __shfl_xor(pmax, 32));
      float mn = fmaxf(m, pmax);
      alpha = exp2f(m - mn);
      m = mn;
    }
    float pv[4][4];
    #pragma unroll
    for (int t = 0; t < 4; ++t)
      #pragma unroll
      for (int r = 0; r < 4; ++r) pv[t][r] = exp2f(s[t][r] - m);
    u32x4 pa0, pa1;
    pa0[0] = pkrtz(pv[0][0], pv[0][1]); pa0[1] = pkrtz(pv[0][2], pv[0][3]);
    pa0[2] = pkrtz(pv[2][0], pv[2][1]); pa0[3] = pkrtz(pv[2][2], pv[2][3]);
    pa1[0] = pkrtz(pv[1][0], pv[1][1]); pa1[1] = pkrtz(pv[1][2], pv[1][3]);
    pa1[2] = pkrtz(pv[3][0], pv[3][1]); pa1[3] = pkrtz(pv[3][2], pv[3][3]);
    Pex[par][half][wi][0][lane] = pa0;
    Pex[par][half][wi][1][lane] = pa1;
    if (lane < 16) alphaL[par][half][wi][lane] = alpha;
  };

  // ---- prologue: tile 0 -> parity 0
  #pragma unroll
  for (int t = 0; t < 4; ++t)
    Kf[t] = *reinterpret_cast<const f16x8*>(
        Kb + (size_t)(mbase + 32 * (t & 1) + 4 * (t >> 1)) * DQK);
  qk_softmax(0);
  BAR();

  const int NIT = HW / 2 / 64;   // 32
  for (int it = 0; it < NIT; ++it) {
    const int prt = it & 1;
    const bool notlast = (it + 1 < NIT);
    const int m0 = mbase + it * 64;
    const int mnext = m0 + 64;
    // A: prefetch next K (in flight across PV-kk0)
    if (notlast) {
      #pragma unroll
      for (int t = 0; t < 4; ++t)
        Kf[t] = *reinterpret_cast<const f16x8*>(
            Kb + (size_t)(mnext + 32 * (t & 1) + 4 * (t >> 1)) * DQK);
    }
    // B: rescale O with this tile's alphas (broadcast reads, branch wave-uniform)
    #pragma unroll
    for (int tr = 0; tr < 4; ++tr) {
      f32x4 al = *reinterpret_cast<const f32x4*>(&alphaL[prt][half][tr][4 * lk]);
      int diff = (al[0] != 1.f) | (al[1] != 1.f) | (al[2] != 1.f) | (al[3] != 1.f);
      if (__any(diff)) {
        #pragma unroll
        for (int tc = 0; tc < 3; ++tc) {
          O[tr * 3 + tc][0] *= al[0]; O[tr * 3 + tc][1] *= al[1];
          O[tr * 3 + tc][2] *= al[2]; O[tr * 3 + tc][3] *= al[3];
        }
        if (tr == wi) {
          lacc[0] *= al[0]; lacc[1] *= al[1]; lacc[2] *= al[2]; lacc[3] *= al[3];
        }
      }
    }
    // C0: PV kk=0
    {
      f16x8 paf[4];
      #pragma unroll
      for (int tr = 0; tr < 4; ++tr)
        paf[tr] = __builtin_bit_cast(f16x8, Pex[prt][half][tr][0][lane]);
      f16x8 pw = __builtin_bit_cast(f16x8, Pex[prt][half][wi][0][lane]);
      lacc = __builtin_amdgcn_mfma_f32_16x16x32_f16(pw, vones, lacc, 0, 0, 0);
      #pragma unroll
      for (int tc = 0; tc < 3; ++tc) {
        f16x8 vb = *reinterpret_cast<const f16x8*>(
            Vw + (size_t)tc * 16 * HW + m0);
        #pragma unroll
        for (int tr = 0; tr < 4; ++tr)
          O[tr * 3 + tc] = __builtin_amdgcn_mfma_f32_16x16x32_f16(
              paf[tr], vb, O[tr * 3 + tc], 0, 0, 0);
      }
    }
    // E: next tile's QK + softmax + P write (overlaps other waves' PV)
    if (notlast) qk_softmax(prt ^ 1);
    // C1: PV kk=1
    {
      f16x8 paf[4];
      #pragma unroll
      for (int tr = 0; tr < 4; ++tr)
        paf[tr] = __builtin_bit_cast(f16x8, Pex[prt][half][tr][1][lane]);
      f16x8 pw = __builtin_bit_cast(f16x8, Pex[prt][half][wi][1][lane]);
      lacc = __builtin_amdgcn_mfma_f32_16x16x32_f16(pw, vones, lacc, 0, 0, 0);
      #pragma unroll
      for (int tc = 0; tc < 3; ++tc) {
        f16x8 vb = *reinterpret_cast<const f16x8*>(
            Vw + (size_t)tc * 16 * HW + m0 + 32);
        #pragma unroll
        for (int tr = 0; tr < 4; ++tr)
          O[tr * 3 + tc] = __builtin_amdgcn_mfma_f32_16x16x32_f16(
              paf[tr], vb, O[tr * 3 + tc], 0, 0, 0);
      }
    }
    BAR();
  }

  // ---- cross-half merge, staged through the Pex area (2 chunks)
  if (lane < 16) mlL[half][0][16 * wi + lane] = m;
  if (lq == 0) {
    #pragma unroll
    for (int r = 0; r < 4; ++r) mlL[half][1][16 * wi + 4 * lk + r] = lacc[r];
  }
  f32x4* Ost = reinterpret_cast<f32x4*>(&Pex[0][0][0][0][0]);
  if (half == 1) {
    #pragma unroll
    for (int i = 0; i < 8; ++i) Ost[(wi * 8 + i) * 64 + lane] = O[i];
  }
  BAR();
  f32x4 f0v[4], f1v[4];
  if (half == 0) {
    #pragma unroll
    for (int tr = 0; tr < 4; ++tr) {
      f32x4 m0v = *reinterpret_cast<const f32x4*>(&mlL[0][0][16 * tr + 4 * lk]);
      f32x4 l0v = *reinterpret_cast<const f32x4*>(&mlL[0][1][16 * tr + 4 * lk]);
      f32x4 m1v = *reinterpret_cast<const f32x4*>(&mlL[1][0][16 * tr + 4 * lk]);
      f32x4 l1v = *reinterpret_cast<const f32x4*>(&mlL[1][1][16 * tr + 4 * lk]);
      #pragma unroll
      for (int r = 0; r < 4; ++r) {
        float M  = fmaxf(m0v[r], m1v[r]);
        float s0 = exp2f(m0v[r] - M), s1 = exp2f(m1v[r] - M);
        float L  = s0 * l0v[r] + s1 * l1v[r];
        f0v[tr][r] = s0 / L; f1v[tr][r] = s1 / L;
      }
    }
    #pragma unroll
    for (int i = 0; i < 8; ++i) {
      const int tr = i / 3, tc = i - tr * 3;
      f32x4 o1 = Ost[(wi * 8 + i) * 64 + lane];
      f32x4 o;
      #pragma unroll
      for (int r = 0; r < 4; ++r) o[r] = O[i][r] * f0v[tr][r] + o1[r] * f1v[tr][r];
      *reinterpret_cast<f32x4*>(
          out + ((size_t)b * NC + wi * 48 + tc * 16 + lq) * HW + q0 + 16 * tr + 4 * lk) = o;
    }
  }
  BAR();
  if (half == 1) {
    #pragma unroll
    for (int i = 0; i < 4; ++i) Ost[(wi * 4 + i) * 64 + lane] = O[8 + i];
  }
  BAR();
  if (half == 0) {
    #pragma unroll
    for (int i = 8; i < 12; ++i) {
      const int tr = i / 3, tc = i - tr * 3;
      f32x4 o1 = Ost[(wi * 4 + (i - 8)) * 64 + lane];
      f32x4 o;
      #pragma unroll
      for (int r = 0; r < 4; ++r) o[r] = O[i][r] * f0v[tr][r] + o1[r] * f1v[tr][r];
      *reinterpret_cast<f32x4*>(
          out + ((size_t)b * NC + wi * 48 + tc * 16 + lq) * HW + q0 + 16 * tr + 4 * lk) = o;
    }
  }
}

extern "C" void kernel_launch(void* const* d_in, const int* in_sizes, int n_in,
                              void* d_out, int out_size, void* d_ws, size_t ws_size,
                              hipStream_t stream) {
  const float* x  = (const float*)d_in[0];
  const float* w1 = (const float*)d_in[1];
  const float* b1 = (const float*)d_in[2];
  const float* a1 = (const float*)d_in[3];
  const float* w2 = (const float*)d_in[4];
  const float* b2 = (const float*)d_in[5];
  const float* a2 = (const float*)d_in[6];
  const float* wa = (const float*)d_in[7];
  const float* ba = (const float*)d_in[8];
  const float* aa = (const float*)d_in[9];
  float* out = (float*)d_out;

  unsigned short* Qn = (unsigned short*)d_ws;                 // 2 MB
  unsigned short* Kn = Qn + (size_t)NB * HW * DQK;            // 2 MB
  unsigned short* Vt = Kn + (size_t)NB * HW * DQK;            // 12 MB
  float* wt = out + (out_size - 49152);                       // 194*240 floats used

  (void)hipMemsetAsync(Qn, 0, (size_t)NB * HW * DQK * 2 * sizeof(unsigned short), stream);

  wtrans_kernel<<<dim3(194), 256, 0, stream>>>(w1, b1, a1, w2, b2, a2, wa, ba, aa, wt);

  dim3 pgrid(HW * NB / 512, 15);
  proj_kernel<<<pgrid, 256, 0, stream>>>(x, wt, Qn, Kn, Vt);

  dim3 fgrid(HW / 64, NB);
  flash_kernel<<<fgrid, 512, 0, stream>>>(Qn, Kn, Vt, out);
}